// Round 8
// baseline (362.619 us; speedup 1.0000x reference)
//
#include <hip/hip_runtime.h>
#include <hip/hip_bf16.h>
#include <math.h>

// GCN 2-layer: h = Ddst^-1/2 A (Dsrc^-1/2 x) W + b, relu between.
// R17: gemm1 v3 — no-LDS, no-barrier, B-IN-REGISTERS. 256 thr/block, block
// covers 16 rows; 4 waves each own a 32-col slice -> per lane only 16
// B-frags (64 VGPR) for the whole K=256, hoisted into a static array and
// loaded once from L2-resident W1t (R11's failure was compiler serializing
// B loads at VGPR=52; explicit hoist + __launch_bounds__(256,4) fixes it).
// norm_src moved to the fp32 epilogue (kills 16 VALU muls/chunk, slightly
// better numerics). Waves' duplicated X reads (same 16 rows) are L1-served.
// R16's fused spmm1+MFMA-projection (gemm2 eliminated), histogram CSR
// build, and fp16 h2/spmm2 retained byte-identical.
// 2x400MB harness poison fills (~119us) sit inside the timed window.

#define F_IN  256
#define F_HID 128
#define F_CLS 40

#define RSZ 8192    // nodes per histogram range (32KB LDS)
#define NSL 32      // edge slices

typedef __bf16 bf16_t;
typedef bf16_t bf16x8 __attribute__((ext_vector_type(8)));
typedef float floatx4 __attribute__((ext_vector_type(4)));
typedef _Float16 f16x8 __attribute__((ext_vector_type(8)));

static __device__ __forceinline__ unsigned short f2b(float f) {
    __hip_bfloat16 h = __float2bfloat16(f);   // RNE
    return __builtin_bit_cast(unsigned short, h);
}
static __device__ __forceinline__ float b2f(unsigned short u) {
    return __uint_as_float((unsigned)u << 16);
}
static __device__ __forceinline__ unsigned short f2h(float f) {
    return __builtin_bit_cast(unsigned short, (_Float16)f);
}
static __device__ __forceinline__ float h2f(unsigned short u) {
    return (float)__builtin_bit_cast(_Float16, u);
}

// ---- histogram partials: block (r, sl, y) counts keys-in-range from slice --
__global__ __launch_bounds__(256) void hist_kernel(
    const int* __restrict__ src, const int* __restrict__ dst,
    unsigned* __restrict__ partial_s, unsigned* __restrict__ partial_d, int E)
{
    __shared__ unsigned h[RSZ];
    const int t = threadIdx.x;
    const int r  = blockIdx.x / NSL;
    const int sl = blockIdx.x % NSL;
    const int lo = r * RSZ;
    const int* __restrict__ keys = blockIdx.y ? dst : src;
    unsigned* __restrict__ part = blockIdx.y ? partial_d : partial_s;

    for (int i = t; i < RSZ; i += 256) h[i] = 0;
    __syncthreads();

    const int slice = (E + NSL - 1) / NSL;
    const int e0 = sl * slice;
    const int e1 = min(E, e0 + slice);

    int e = e0 + t;
    for (; e + 7 * 256 < e1; e += 8 * 256) {
        int k[8];
        #pragma unroll
        for (int i = 0; i < 8; ++i) k[i] = keys[e + i * 256];
        #pragma unroll
        for (int i = 0; i < 8; ++i) {
            unsigned kk = (unsigned)(k[i] - lo);
            if (kk < RSZ) atomicAdd(&h[kk], 1u);
        }
    }
    for (; e < e1; e += 256) {
        unsigned kk = (unsigned)(keys[e] - lo);
        if (kk < RSZ) atomicAdd(&h[kk], 1u);
    }
    __syncthreads();

    unsigned* dst_p = part + (size_t)blockIdx.x * RSZ;
    for (int i = t; i < RSZ; i += 256) dst_p[i] = h[i];
}

// ---- scan1: reduce partials -> norms + block-local exclusive scan ----------
__global__ __launch_bounds__(256) void scan1_kernel(
    const unsigned* __restrict__ partial_s, const unsigned* __restrict__ partial_d,
    int* __restrict__ row_off, int* __restrict__ blk_sums,
    float* __restrict__ norm_src, float* __restrict__ norm_dst, int N)
{
    __shared__ int s[256];
    const int t = threadIdx.x;
    const int base = blockIdx.x * 1024 + t * 4;

    unsigned ss0 = 0, ss1 = 0, ss2 = 0, ss3 = 0;
    unsigned sd0 = 0, sd1 = 0, sd2 = 0, sd3 = 0;
    {
        // base..base+3 never cross an RSZ boundary (both multiples of 4)
        const int r = base / RSZ;
        const int off = base & (RSZ - 1);
        const unsigned* ps = partial_s + (size_t)r * NSL * RSZ + off;
        const unsigned* pd = partial_d + (size_t)r * NSL * RSZ + off;
        #pragma unroll
        for (int sl = 0; sl < NSL; ++sl) {
            uint4 a = *(const uint4*)(ps + (size_t)sl * RSZ);
            uint4 b = *(const uint4*)(pd + (size_t)sl * RSZ);
            ss0 += a.x; ss1 += a.y; ss2 += a.z; ss3 += a.w;
            sd0 += b.x; sd1 += b.y; sd2 += b.z; sd3 += b.w;
        }
    }
    if (base + 0 < N) {
        norm_src[base + 0] = ss0 ? 1.0f / sqrtf((float)ss0) : 0.0f;
        norm_dst[base + 0] = sd0 ? 1.0f / sqrtf((float)sd0) : 0.0f;
    }
    if (base + 1 < N) {
        norm_src[base + 1] = ss1 ? 1.0f / sqrtf((float)ss1) : 0.0f;
        norm_dst[base + 1] = sd1 ? 1.0f / sqrtf((float)sd1) : 0.0f;
    }
    if (base + 2 < N) {
        norm_src[base + 2] = ss2 ? 1.0f / sqrtf((float)ss2) : 0.0f;
        norm_dst[base + 2] = sd2 ? 1.0f / sqrtf((float)sd2) : 0.0f;
    }
    if (base + 3 < N) {
        norm_src[base + 3] = ss3 ? 1.0f / sqrtf((float)ss3) : 0.0f;
        norm_dst[base + 3] = sd3 ? 1.0f / sqrtf((float)sd3) : 0.0f;
    }

    int v0 = (base + 0 < N) ? (int)sd0 : 0;
    int v1 = (base + 1 < N) ? (int)sd1 : 0;
    int v2 = (base + 2 < N) ? (int)sd2 : 0;
    int v3 = (base + 3 < N) ? (int)sd3 : 0;
    int local = v0 + v1 + v2 + v3;
    s[t] = local;
    __syncthreads();
    for (int off = 1; off < 256; off <<= 1) {
        int x = (t >= off) ? s[t - off] : 0;
        __syncthreads();
        s[t] += x;
        __syncthreads();
    }
    int excl = s[t] - local;
    if (t == 255) blk_sums[blockIdx.x] = s[t];
    if (base + 0 < N) row_off[base + 0] = excl;
    if (base + 1 < N) row_off[base + 1] = excl + v0;
    if (base + 2 < N) row_off[base + 2] = excl + v0 + v1;
    if (base + 3 < N) row_off[base + 3] = excl + v0 + v1 + v2;
}

// ---- scan2 (block 0) + pack W1->W1t (blocks 1..128) + W2->W2t (129..152) ---
// W1t [128][256] bf16 n-major k-contig; W2t [48][128] fp16 n-major k-contig
// (rows 40..47 zero) -- both match the gemm1/MFMA B-frag layout.
__global__ __launch_bounds__(256) void scan2_pack_kernel(
    int* __restrict__ blk_sums, int B,
    const float* __restrict__ W1, __hip_bfloat16* __restrict__ W1t,
    const float* __restrict__ W2, unsigned short* __restrict__ W2t)
{
    const int t = threadIdx.x;
    if (blockIdx.x > 128) {
        int idx = (blockIdx.x - 129) * 256 + t;   // 0..6143
        int n = idx >> 7;                         // 0..47
        int k = idx & 127;
        W2t[idx] = (n < F_CLS) ? f2h(W2[(size_t)k * F_CLS + n]) : (unsigned short)0;
        return;
    }
    if (blockIdx.x > 0) {
        int idx = (blockIdx.x - 1) * 256 + t;     // 0..32767
        int n = idx >> 8;
        int k = idx & 255;
        W1t[idx] = __float2bfloat16(W1[(size_t)k * F_HID + n]);
        return;
    }
    __shared__ int s[256];
    int local = (t < B) ? blk_sums[t] : 0;
    s[t] = local;
    __syncthreads();
    for (int off = 1; off < 256; off <<= 1) {
        int x = (t >= off) ? s[t - off] : 0;
        __syncthreads();
        s[t] += x;
        __syncthreads();
    }
    if (t < B) blk_sums[t] = s[t] - local;   // exclusive
}

// ---- scan3+slicepref fused: finalize row_off and convert partial_d counts
//      into absolute CSR cursors (in-place exclusive scan over slices) -------
__global__ __launch_bounds__(256) void scan3_slicepref_kernel(
    int* __restrict__ row_off, const int* __restrict__ blk_sums,
    unsigned* __restrict__ partial_d, int N, int E, int NRtot)
{
    const int idx = blockIdx.x * 256 + threadIdx.x;   // node id (incl. pad)
    if (idx >= NRtot) return;
    unsigned run = 0;
    if (idx < N) {
        int v = row_off[idx] + blk_sums[idx >> 10];
        row_off[idx] = v;
        run = (unsigned)v;
    }
    if (idx == N) row_off[N] = E;
    const int r = idx / RSZ;
    const int i = idx & (RSZ - 1);
    unsigned* p = partial_d + (size_t)r * NSL * RSZ + i;
    #pragma unroll
    for (int sl = 0; sl < NSL; ++sl) {
        unsigned c = p[(size_t)sl * RSZ];
        p[(size_t)sl * RSZ] = run;
        run += c;
    }
}

// ---- scatter edges into CSR via LDS cursors (no global atomics) ------------
__global__ __launch_bounds__(256) void scatter2_kernel(
    const int* __restrict__ src, const int* __restrict__ dst,
    const unsigned* __restrict__ pref, int* __restrict__ csr_src, int E)
{
    __shared__ unsigned cur[RSZ];
    const int t = threadIdx.x;
    const int r  = blockIdx.x / NSL;
    const int sl = blockIdx.x % NSL;
    const int lo = r * RSZ;
    const unsigned* p = pref + (size_t)blockIdx.x * RSZ;   // [r][sl][.]

    for (int i = t; i < RSZ; i += 256) cur[i] = p[i];
    __syncthreads();

    const int slice = (E + NSL - 1) / NSL;
    const int e0 = sl * slice;
    const int e1 = min(E, e0 + slice);

    int e = e0 + t;
    for (; e + 7 * 256 < e1; e += 8 * 256) {
        int d[8], s[8];
        #pragma unroll
        for (int i = 0; i < 8; ++i) { d[i] = dst[e + i * 256]; s[i] = src[e + i * 256]; }
        #pragma unroll
        for (int i = 0; i < 8; ++i) {
            unsigned k = (unsigned)(d[i] - lo);
            if (k < RSZ) {
                unsigned pos = atomicAdd(&cur[k], 1u);
                csr_src[pos] = s[i];
            }
        }
    }
    for (; e < e1; e += 256) {
        unsigned k = (unsigned)(dst[e] - lo);
        if (k < RSZ) {
            unsigned pos = atomicAdd(&cur[k], 1u);
            csr_src[pos] = src[e];
        }
    }
}

// ---- GEMM1 v3 (MFMA, no LDS, no barriers): h1b = bf16( (X @ W1)*ns ) -------
// 256 thr = 4 waves; block covers 16 rows (node0..node0+15). Wave w owns
// cols [w*32, w*32+32): per lane 16 B-frags (2 nt x 4 chunks x 2 halves)
// hoisted into registers, loaded once from L2-resident W1t. K-loop is pure
// {convert, prefetch, 4x MFMA}. ns applied in fp32 epilogue.
__global__ __launch_bounds__(256, 4) void gemm1_mfma_kernel(
    const float* __restrict__ X, const __hip_bfloat16* __restrict__ W1t,
    const float* __restrict__ norm_src, __hip_bfloat16* __restrict__ h1b, int N)
{
    const int t = threadIdx.x;
    const int node0 = blockIdx.x * 16;
    const int w = t >> 6;               // wave 0..3 -> col slice w*32
    const int lane = t & 63;
    const int l15 = lane & 15;
    const int quad = lane >> 4;

    const int arow = node0 + l15;
    const int arow_c = (arow < N) ? arow : (N - 1);
    const float* xp = X + (size_t)arow_c * F_IN + quad * 8;

    // issue X chunk-0 loads first (HBM latency ~900cy; B loads below are L2)
    float4 araw[4];
    araw[0] = *(const float4*)(xp + 0);
    araw[1] = *(const float4*)(xp + 4);
    araw[2] = *(const float4*)(xp + 32);
    araw[3] = *(const float4*)(xp + 36);

    // hoist ALL 16 B-frags into registers (static indexing -> stays in VGPRs;
    // 16 independent dwordx4 loads issue back-to-back, one L2 latency total)
    bf16x8 bfr[2][4][2];
    #pragma unroll
    for (int nt = 0; nt < 2; ++nt) {
        const __hip_bfloat16* bp = W1t + (size_t)((w * 2 + nt) * 16 + l15) * F_IN
                                       + quad * 8;
        #pragma unroll
        for (int c = 0; c < 4; ++c) {
            #pragma unroll
            for (int h = 0; h < 2; ++h)
                bfr[nt][c][h] = *(const bf16x8*)(bp + c * 64 + h * 32);
        }
    }

    floatx4 acc[2] = {};

    #pragma unroll
    for (int c = 0; c < 4; ++c) {
        bf16x8 ab0, ab1;
        {
            union { bf16x8 v; unsigned short u[8]; } cv;
            cv.u[0] = f2b(araw[0].x); cv.u[1] = f2b(araw[0].y);
            cv.u[2] = f2b(araw[0].z); cv.u[3] = f2b(araw[0].w);
            cv.u[4] = f2b(araw[1].x); cv.u[5] = f2b(araw[1].y);
            cv.u[6] = f2b(araw[1].z); cv.u[7] = f2b(araw[1].w);
            ab0 = cv.v;
            cv.u[0] = f2b(araw[2].x); cv.u[1] = f2b(araw[2].y);
            cv.u[2] = f2b(araw[2].z); cv.u[3] = f2b(araw[2].w);
            cv.u[4] = f2b(araw[3].x); cv.u[5] = f2b(araw[3].y);
            cv.u[6] = f2b(araw[3].z); cv.u[7] = f2b(araw[3].w);
            ab1 = cv.v;
        }
        if (c < 3) {
            araw[0] = *(const float4*)(xp + (c + 1) * 64 + 0);
            araw[1] = *(const float4*)(xp + (c + 1) * 64 + 4);
            araw[2] = *(const float4*)(xp + (c + 1) * 64 + 32);
            araw[3] = *(const float4*)(xp + (c + 1) * 64 + 36);
        }
        #pragma unroll
        for (int nt = 0; nt < 2; ++nt) {
            acc[nt] = __builtin_amdgcn_mfma_f32_16x16x32_bf16(ab0, bfr[nt][c][0],
                                                              acc[nt], 0, 0, 0);
            acc[nt] = __builtin_amdgcn_mfma_f32_16x16x32_bf16(ab1, bfr[nt][c][1],
                                                              acc[nt], 0, 0, 0);
        }
    }

    // epilogue: scale by norm_src of the OUTPUT row (C row = quad*4 + r)
    #pragma unroll
    for (int r = 0; r < 4; ++r) {
        int node = node0 + quad * 4 + r;
        if (node < N) {
            float ns = norm_src[node];
            #pragma unroll
            for (int nt = 0; nt < 2; ++nt) {
                int col = (w * 2 + nt) * 16 + l15;
                h1b[(size_t)node * F_HID + col] = __float2bfloat16(acc[nt][r] * ns);
            }
        }
    }
}

// ---- SpMM1 + layer-1 epilogue + fused MFMA projection to h2 ----------------
// 16 nodes/block (512 thr), 32 lanes/node: gather h1b rows, activate, store
// fp16 row to LDS As[16][136] (pad->bank-spread, 16B-aligned frags). Then
// wave 0 computes h2[16 nodes][40] = As @ W2t via 12x mfma_f32_16x16x32_f16
// (A-frag: As[l15][kc*32+quad*8..+8); B-frag: W2t[ct*16+l15][same k] from L2).
__global__ __launch_bounds__(512) void spmm1_fused_kernel(
    const __hip_bfloat16* __restrict__ h1b, const int* __restrict__ row_off,
    const int* __restrict__ csr_src, const float* __restrict__ norm_src,
    const float* __restrict__ norm_dst, const float* __restrict__ b1,
    const unsigned short* __restrict__ W2t, unsigned short* __restrict__ h2, int N)
{
    __shared__ unsigned short As[16][136];
    const int t = threadIdx.x;
    const int g = t >> 5;
    const int node = blockIdx.x * 16 + g;
    const int c = (t & 31) << 2;

    if (node < N) {
        const int start = row_off[node];
        const int end = row_off[node + 1];
        float4 acc = make_float4(0.f, 0.f, 0.f, 0.f);
        int j = start;
        for (; j + 8 <= end; j += 8) {
            int s[8];
            #pragma unroll
            for (int i = 0; i < 8; ++i) s[i] = csr_src[j + i];
            ushort4 u[8];
            #pragma unroll
            for (int i = 0; i < 8; ++i)
                u[i] = *(const ushort4*)(h1b + (size_t)s[i] * F_HID + c);
            #pragma unroll
            for (int i = 0; i < 8; ++i) {
                acc.x += b2f(u[i].x);
                acc.y += b2f(u[i].y);
                acc.z += b2f(u[i].z);
                acc.w += b2f(u[i].w);
            }
        }
        for (; j + 2 <= end; j += 2) {
            int s0 = csr_src[j + 0];
            int s1 = csr_src[j + 1];
            ushort4 u0 = *(const ushort4*)(h1b + (size_t)s0 * F_HID + c);
            ushort4 u1 = *(const ushort4*)(h1b + (size_t)s1 * F_HID + c);
            acc.x += b2f(u0.x) + b2f(u1.x);
            acc.y += b2f(u0.y) + b2f(u1.y);
            acc.z += b2f(u0.z) + b2f(u1.z);
            acc.w += b2f(u0.w) + b2f(u1.w);
        }
        if (j < end) {
            int s = csr_src[j];
            ushort4 u = *(const ushort4*)(h1b + (size_t)s * F_HID + c);
            acc.x += b2f(u.x);
            acc.y += b2f(u.y);
            acc.z += b2f(u.z);
            acc.w += b2f(u.w);
        }
        const float nd = norm_dst[node];
        const float ns = norm_src[node];
        float4 bb = *(const float4*)(b1 + c);
        ushort4 o;
        o.x = f2h(fmaxf(fmaf(acc.x, nd, bb.x), 0.f) * ns);
        o.y = f2h(fmaxf(fmaf(acc.y, nd, bb.y), 0.f) * ns);
        o.z = f2h(fmaxf(fmaf(acc.z, nd, bb.z), 0.f) * ns);
        o.w = f2h(fmaxf(fmaf(acc.w, nd, bb.w), 0.f) * ns);
        *(ushort4*)&As[g][c] = o;
    } else {
        ushort4 z = make_ushort4(0, 0, 0, 0);
        *(ushort4*)&As[g][c] = z;
    }
    __syncthreads();
    if (t >= 64) return;

    const int l15 = t & 15;
    const int quad = t >> 4;
    floatx4 co[3] = {};
    #pragma unroll
    for (int kc = 0; kc < 4; ++kc) {
        f16x8 a = *(const f16x8*)&As[l15][kc * 32 + quad * 8];
        #pragma unroll
        for (int ct = 0; ct < 3; ++ct) {
            f16x8 b = *(const f16x8*)(W2t + (size_t)(ct * 16 + l15) * F_HID
                                          + kc * 32 + quad * 8);
            co[ct] = __builtin_amdgcn_mfma_f32_16x16x32_f16(a, b, co[ct], 0, 0, 0);
        }
    }
    const int node0 = blockIdx.x * 16;
    #pragma unroll
    for (int ct = 0; ct < 3; ++ct) {
        int col = ct * 16 + l15;
        if (col < F_CLS) {
            #pragma unroll
            for (int i = 0; i < 4; ++i) {
                int n2 = node0 + quad * 4 + i;
                if (n2 < N) h2[(size_t)n2 * F_CLS + col] = f2h(co[ct][i]);
            }
        }
    }
}

// ---- SpMM2 (CSR, fp16 gather) + epilogue: out = (sum h2[src,:])*nd + b2 ----
// 25 nodes/block, 10 lanes/node (250/256 active), 8-deep gather batching.
__global__ __launch_bounds__(256) void spmm2_csr_kernel(
    const unsigned short* __restrict__ h2, const int* __restrict__ row_off,
    const int* __restrict__ csr_src, const float* __restrict__ norm_dst,
    const float* __restrict__ b2, float* __restrict__ out, int N)
{
    const int t = threadIdx.x;
    if (t >= 250) return;
    const int node = blockIdx.x * 25 + t / 10;
    const int lane = t % 10;
    if (node >= N) return;
    const int c = lane << 2;
    const int start = row_off[node];
    const int end = row_off[node + 1];
    float4 acc = make_float4(0.f, 0.f, 0.f, 0.f);
    int j = start;
    for (; j + 8 <= end; j += 8) {
        int s[8];
        #pragma unroll
        for (int i = 0; i < 8; ++i) s[i] = csr_src[j + i];
        ushort4 u[8];
        #pragma unroll
        for (int i = 0; i < 8; ++i)
            u[i] = *(const ushort4*)(h2 + (size_t)s[i] * F_CLS + c);
        #pragma unroll
        for (int i = 0; i < 8; ++i) {
            acc.x += h2f(u[i].x);
            acc.y += h2f(u[i].y);
            acc.z += h2f(u[i].z);
            acc.w += h2f(u[i].w);
        }
    }
    for (; j + 2 <= end; j += 2) {
        int s0 = csr_src[j + 0];
        int s1 = csr_src[j + 1];
        ushort4 u0 = *(const ushort4*)(h2 + (size_t)s0 * F_CLS + c);
        ushort4 u1 = *(const ushort4*)(h2 + (size_t)s1 * F_CLS + c);
        acc.x += h2f(u0.x) + h2f(u1.x);
        acc.y += h2f(u0.y) + h2f(u1.y);
        acc.z += h2f(u0.z) + h2f(u1.z);
        acc.w += h2f(u0.w) + h2f(u1.w);
    }
    if (j < end) {
        int s = csr_src[j];
        ushort4 u = *(const ushort4*)(h2 + (size_t)s * F_CLS + c);
        acc.x += h2f(u.x);
        acc.y += h2f(u.y);
        acc.z += h2f(u.z);
        acc.w += h2f(u.w);
    }
    float nd = norm_dst[node];
    float4 bb = *(const float4*)(b2 + c);
    float4 r;
    r.x = fmaf(acc.x, nd, bb.x);
    r.y = fmaf(acc.y, nd, bb.y);
    r.z = fmaf(acc.z, nd, bb.z);
    r.w = fmaf(acc.w, nd, bb.w);
    *(float4*)(out + (size_t)node * F_CLS + c) = r;
}

extern "C" void kernel_launch(void* const* d_in, const int* in_sizes, int n_in,
                              void* d_out, int out_size, void* d_ws, size_t ws_size,
                              hipStream_t stream) {
    const float* X   = (const float*)d_in[0];
    const int*   src = (const int*)d_in[1];
    const int*   dst = (const int*)d_in[2];
    const float* W1  = (const float*)d_in[3];
    const float* b1  = (const float*)d_in[4];
    const float* W2  = (const float*)d_in[5];
    const float* b2  = (const float*)d_in[6];
    float* out = (float*)d_out;

    const int N = in_sizes[0] / F_IN;
    const int E = in_sizes[1];
    const int NB = (N + 1023) / 1024;     // scan blocks (<= 256)
    const int NR = (N + RSZ - 1) / RSZ;   // histogram ranges
    const int NRtot = NR * RSZ;

    // workspace layout — keep every array 16B-aligned
    char* w = (char*)d_ws;
    int*   row_off  = (int*)w;                      w += (size_t)(N + 4) * 4;
    int*   blk_sums = (int*)w;                      w += 256 * 4;
    int*   csr_src  = (int*)w;                      w += (size_t)E * 4;
    float* norm_src = (float*)w;                    w += (size_t)N * 4;
    float* norm_dst = (float*)w;                    w += (size_t)N * 4;
    unsigned short* h2 = (unsigned short*)w;        w += (size_t)N * F_CLS * 2;
    __hip_bfloat16* W1t = (__hip_bfloat16*)w;       w += (size_t)F_HID * F_IN * 2;
    unsigned short* W2t = (unsigned short*)w;       w += (size_t)48 * F_HID * 2;
    __hip_bfloat16* h1b = (__hip_bfloat16*)w;       w += (size_t)N * F_HID * 2;
    unsigned* partial_s = (unsigned*)w;             w += (size_t)NR * NSL * RSZ * 4;
    unsigned* partial_d = (unsigned*)w;             w += (size_t)NR * NSL * RSZ * 4;

    hist_kernel<<<dim3(NR * NSL, 2), 256, 0, stream>>>(src, dst, partial_s, partial_d, E);

    scan1_kernel<<<NB, 256, 0, stream>>>(partial_s, partial_d, row_off, blk_sums,
                                         norm_src, norm_dst, N);
    scan2_pack_kernel<<<153, 256, 0, stream>>>(blk_sums, NB, W1, W1t, W2, W2t);
    scan3_slicepref_kernel<<<(NRtot + 255) / 256, 256, 0, stream>>>(
        row_off, blk_sums, partial_d, N, E, NRtot);

    scatter2_kernel<<<NR * NSL, 256, 0, stream>>>(src, dst, partial_d, csr_src, E);

    gemm1_mfma_kernel<<<(N + 15) / 16, 256, 0, stream>>>(X, W1t, norm_src, h1b, N);

    spmm1_fused_kernel<<<(N + 15) / 16, 512, 0, stream>>>(h1b, row_off, csr_src,
                                                          norm_src, norm_dst, b1,
                                                          W2t, h2, N);

    spmm2_csr_kernel<<<(N + 24) / 25, 256, 0, stream>>>(h2, row_off, csr_src,
                                                        norm_dst, b2, out, N);
}

// Round 9
// 301.962 us; speedup vs baseline: 1.2009x; 1.2009x over previous
//
#include <hip/hip_runtime.h>
#include <hip/hip_bf16.h>
#include <math.h>

// GCN 2-layer: h = Ddst^-1/2 A (Dsrc^-1/2 x) W + b, relu between.
// R18: REVERT gemm1 to the R12/R16 single-barrier 64KB-LDS version.
// R17's B-in-registers gemm1 hit the R11 failure mode again: hipcc sinks
// global loads to minimize VGPR (measured VGPR=32 -> the 16 hoisted B-frags
// were rematerialized inside the K-loop, load->wait->MFMA serial, 118us).
// LEDGER: explicit static reg arrays do NOT defeat load sinking; LDS staging
// is the reliable way to keep B off the latency path.
// Everything else byte-identical to R16 (301.5us session best): fused
// spmm1+MFMA projection (gemm2 eliminated), histogram CSR build with scan
// fusions, fp16 h2/spmm2.
// 2x400MB harness poison fills (~119us) sit inside the timed window.

#define F_IN  256
#define F_HID 128
#define F_CLS 40

#define RSZ 8192    // nodes per histogram range (32KB LDS)
#define NSL 32      // edge slices

typedef __bf16 bf16_t;
typedef bf16_t bf16x8 __attribute__((ext_vector_type(8)));
typedef float floatx4 __attribute__((ext_vector_type(4)));
typedef _Float16 f16x8 __attribute__((ext_vector_type(8)));

static __device__ __forceinline__ unsigned short f2b(float f) {
    __hip_bfloat16 h = __float2bfloat16(f);   // RNE
    return __builtin_bit_cast(unsigned short, h);
}
static __device__ __forceinline__ float b2f(unsigned short u) {
    return __uint_as_float((unsigned)u << 16);
}
static __device__ __forceinline__ unsigned short f2h(float f) {
    return __builtin_bit_cast(unsigned short, (_Float16)f);
}
static __device__ __forceinline__ float h2f(unsigned short u) {
    return (float)__builtin_bit_cast(_Float16, u);
}

// ---- histogram partials: block (r, sl, y) counts keys-in-range from slice --
__global__ __launch_bounds__(256) void hist_kernel(
    const int* __restrict__ src, const int* __restrict__ dst,
    unsigned* __restrict__ partial_s, unsigned* __restrict__ partial_d, int E)
{
    __shared__ unsigned h[RSZ];
    const int t = threadIdx.x;
    const int r  = blockIdx.x / NSL;
    const int sl = blockIdx.x % NSL;
    const int lo = r * RSZ;
    const int* __restrict__ keys = blockIdx.y ? dst : src;
    unsigned* __restrict__ part = blockIdx.y ? partial_d : partial_s;

    for (int i = t; i < RSZ; i += 256) h[i] = 0;
    __syncthreads();

    const int slice = (E + NSL - 1) / NSL;
    const int e0 = sl * slice;
    const int e1 = min(E, e0 + slice);

    int e = e0 + t;
    for (; e + 7 * 256 < e1; e += 8 * 256) {
        int k[8];
        #pragma unroll
        for (int i = 0; i < 8; ++i) k[i] = keys[e + i * 256];
        #pragma unroll
        for (int i = 0; i < 8; ++i) {
            unsigned kk = (unsigned)(k[i] - lo);
            if (kk < RSZ) atomicAdd(&h[kk], 1u);
        }
    }
    for (; e < e1; e += 256) {
        unsigned kk = (unsigned)(keys[e] - lo);
        if (kk < RSZ) atomicAdd(&h[kk], 1u);
    }
    __syncthreads();

    unsigned* dst_p = part + (size_t)blockIdx.x * RSZ;
    for (int i = t; i < RSZ; i += 256) dst_p[i] = h[i];
}

// ---- scan1: reduce partials -> norms + block-local exclusive scan ----------
__global__ __launch_bounds__(256) void scan1_kernel(
    const unsigned* __restrict__ partial_s, const unsigned* __restrict__ partial_d,
    int* __restrict__ row_off, int* __restrict__ blk_sums,
    float* __restrict__ norm_src, float* __restrict__ norm_dst, int N)
{
    __shared__ int s[256];
    const int t = threadIdx.x;
    const int base = blockIdx.x * 1024 + t * 4;

    unsigned ss0 = 0, ss1 = 0, ss2 = 0, ss3 = 0;
    unsigned sd0 = 0, sd1 = 0, sd2 = 0, sd3 = 0;
    {
        // base..base+3 never cross an RSZ boundary (both multiples of 4)
        const int r = base / RSZ;
        const int off = base & (RSZ - 1);
        const unsigned* ps = partial_s + (size_t)r * NSL * RSZ + off;
        const unsigned* pd = partial_d + (size_t)r * NSL * RSZ + off;
        #pragma unroll
        for (int sl = 0; sl < NSL; ++sl) {
            uint4 a = *(const uint4*)(ps + (size_t)sl * RSZ);
            uint4 b = *(const uint4*)(pd + (size_t)sl * RSZ);
            ss0 += a.x; ss1 += a.y; ss2 += a.z; ss3 += a.w;
            sd0 += b.x; sd1 += b.y; sd2 += b.z; sd3 += b.w;
        }
    }
    if (base + 0 < N) {
        norm_src[base + 0] = ss0 ? 1.0f / sqrtf((float)ss0) : 0.0f;
        norm_dst[base + 0] = sd0 ? 1.0f / sqrtf((float)sd0) : 0.0f;
    }
    if (base + 1 < N) {
        norm_src[base + 1] = ss1 ? 1.0f / sqrtf((float)ss1) : 0.0f;
        norm_dst[base + 1] = sd1 ? 1.0f / sqrtf((float)sd1) : 0.0f;
    }
    if (base + 2 < N) {
        norm_src[base + 2] = ss2 ? 1.0f / sqrtf((float)ss2) : 0.0f;
        norm_dst[base + 2] = sd2 ? 1.0f / sqrtf((float)sd2) : 0.0f;
    }
    if (base + 3 < N) {
        norm_src[base + 3] = ss3 ? 1.0f / sqrtf((float)ss3) : 0.0f;
        norm_dst[base + 3] = sd3 ? 1.0f / sqrtf((float)sd3) : 0.0f;
    }

    int v0 = (base + 0 < N) ? (int)sd0 : 0;
    int v1 = (base + 1 < N) ? (int)sd1 : 0;
    int v2 = (base + 2 < N) ? (int)sd2 : 0;
    int v3 = (base + 3 < N) ? (int)sd3 : 0;
    int local = v0 + v1 + v2 + v3;
    s[t] = local;
    __syncthreads();
    for (int off = 1; off < 256; off <<= 1) {
        int x = (t >= off) ? s[t - off] : 0;
        __syncthreads();
        s[t] += x;
        __syncthreads();
    }
    int excl = s[t] - local;
    if (t == 255) blk_sums[blockIdx.x] = s[t];
    if (base + 0 < N) row_off[base + 0] = excl;
    if (base + 1 < N) row_off[base + 1] = excl + v0;
    if (base + 2 < N) row_off[base + 2] = excl + v0 + v1;
    if (base + 3 < N) row_off[base + 3] = excl + v0 + v1 + v2;
}

// ---- scan2 (block 0) + pack W1->W1t (blocks 1..128) + W2->W2t (129..152) ---
// W1t [128][256] bf16 n-major k-contig; W2t [48][128] fp16 n-major k-contig
// (rows 40..47 zero) -- both match the gemm1/MFMA B-frag layout.
__global__ __launch_bounds__(256) void scan2_pack_kernel(
    int* __restrict__ blk_sums, int B,
    const float* __restrict__ W1, __hip_bfloat16* __restrict__ W1t,
    const float* __restrict__ W2, unsigned short* __restrict__ W2t)
{
    const int t = threadIdx.x;
    if (blockIdx.x > 128) {
        int idx = (blockIdx.x - 129) * 256 + t;   // 0..6143
        int n = idx >> 7;                         // 0..47
        int k = idx & 127;
        W2t[idx] = (n < F_CLS) ? f2h(W2[(size_t)k * F_CLS + n]) : (unsigned short)0;
        return;
    }
    if (blockIdx.x > 0) {
        int idx = (blockIdx.x - 1) * 256 + t;     // 0..32767
        int n = idx >> 8;
        int k = idx & 255;
        W1t[idx] = __float2bfloat16(W1[(size_t)k * F_HID + n]);
        return;
    }
    __shared__ int s[256];
    int local = (t < B) ? blk_sums[t] : 0;
    s[t] = local;
    __syncthreads();
    for (int off = 1; off < 256; off <<= 1) {
        int x = (t >= off) ? s[t - off] : 0;
        __syncthreads();
        s[t] += x;
        __syncthreads();
    }
    if (t < B) blk_sums[t] = s[t] - local;   // exclusive
}

// ---- scan3+slicepref fused: finalize row_off and convert partial_d counts
//      into absolute CSR cursors (in-place exclusive scan over slices) -------
__global__ __launch_bounds__(256) void scan3_slicepref_kernel(
    int* __restrict__ row_off, const int* __restrict__ blk_sums,
    unsigned* __restrict__ partial_d, int N, int E, int NRtot)
{
    const int idx = blockIdx.x * 256 + threadIdx.x;   // node id (incl. pad)
    if (idx >= NRtot) return;
    unsigned run = 0;
    if (idx < N) {
        int v = row_off[idx] + blk_sums[idx >> 10];
        row_off[idx] = v;
        run = (unsigned)v;
    }
    if (idx == N) row_off[N] = E;
    const int r = idx / RSZ;
    const int i = idx & (RSZ - 1);
    unsigned* p = partial_d + (size_t)r * NSL * RSZ + i;
    #pragma unroll
    for (int sl = 0; sl < NSL; ++sl) {
        unsigned c = p[(size_t)sl * RSZ];
        p[(size_t)sl * RSZ] = run;
        run += c;
    }
}

// ---- scatter edges into CSR via LDS cursors (no global atomics) ------------
__global__ __launch_bounds__(256) void scatter2_kernel(
    const int* __restrict__ src, const int* __restrict__ dst,
    const unsigned* __restrict__ pref, int* __restrict__ csr_src, int E)
{
    __shared__ unsigned cur[RSZ];
    const int t = threadIdx.x;
    const int r  = blockIdx.x / NSL;
    const int sl = blockIdx.x % NSL;
    const int lo = r * RSZ;
    const unsigned* p = pref + (size_t)blockIdx.x * RSZ;   // [r][sl][.]

    for (int i = t; i < RSZ; i += 256) cur[i] = p[i];
    __syncthreads();

    const int slice = (E + NSL - 1) / NSL;
    const int e0 = sl * slice;
    const int e1 = min(E, e0 + slice);

    int e = e0 + t;
    for (; e + 7 * 256 < e1; e += 8 * 256) {
        int d[8], s[8];
        #pragma unroll
        for (int i = 0; i < 8; ++i) { d[i] = dst[e + i * 256]; s[i] = src[e + i * 256]; }
        #pragma unroll
        for (int i = 0; i < 8; ++i) {
            unsigned k = (unsigned)(d[i] - lo);
            if (k < RSZ) {
                unsigned pos = atomicAdd(&cur[k], 1u);
                csr_src[pos] = s[i];
            }
        }
    }
    for (; e < e1; e += 256) {
        unsigned k = (unsigned)(dst[e] - lo);
        if (k < RSZ) {
            unsigned pos = atomicAdd(&cur[k], 1u);
            csr_src[pos] = src[e];
        }
    }
}

// ---- GEMM1 (MFMA): h1b[N,128] = bf16( (X*norm_src)bf16 @ W1bf16 ) ----------
// R12: BM=128, 512 threads (8 waves). Full W1t (64KB) staged to LDS once,
// XOR-swizzled ((row&7)<<3 elements) for conflict-free ds_read_b128.
// One __syncthreads total; K-loop barrier-free. 2 blocks/CU = 16 waves/CU.
__global__ __launch_bounds__(512, 4) void gemm1_mfma_kernel(
    const float* __restrict__ X, const __hip_bfloat16* __restrict__ W1t,
    const float* __restrict__ norm_src, __hip_bfloat16* __restrict__ h1b, int N)
{
    __shared__ __hip_bfloat16 Bs[128 * 256];   // 64KB, rows XOR-swizzled
    const int t = threadIdx.x;
    const int node0 = blockIdx.x * 128;
    const int lane = t & 63;
    const int w = t >> 6;               // wave 0..7 -> 16 rows each
    const int l15 = lane & 15;
    const int quad = lane >> 4;

    const int arow = node0 + w * 16 + l15;
    const bool valid = arow < N;
    const int arow_c = valid ? arow : (N - 1);
    const float ns = valid ? norm_src[arow] : 0.0f;

    const float* xp = X + (size_t)arow_c * F_IN + quad * 8;

    // issue X chunk-0 loads first (HBM latency hides under B staging)
    float4 araw[4];
    araw[0] = *(const float4*)(xp + 0);
    araw[1] = *(const float4*)(xp + 4);
    araw[2] = *(const float4*)(xp + 32);
    araw[3] = *(const float4*)(xp + 36);

    // stage W1t[128][256] -> LDS, reg-staged so dest can carry the XOR swizzle
    // (element index bits 3..5 ^= row&7). 4096 16B-chunks / 512 threads = 8.
    #pragma unroll
    for (int i = 0; i < 8; ++i) {
        int idx = i * 512 + t;
        int row = idx >> 5;             // 0..127
        int ch  = idx & 31;             // 16B chunk within row
        uint4 v = *(const uint4*)(W1t + (size_t)row * F_IN + ch * 8);
        int d = row * 256 + ((ch * 8) ^ ((row & 7) << 3));
        *(uint4*)(Bs + d) = v;
    }
    __syncthreads();

    // per-lane swizzled B base offsets (elements); row = nt*16 + l15 so
    // row&7 == l15&7 independent of nt; c*64 sits above the swizzled bits.
    const int swz = (l15 & 7) << 3;
    const int bbase0 = l15 * 256 + ((quad * 8) ^ swz);
    const int bbase1 = l15 * 256 + ((32 + quad * 8) ^ swz);

    floatx4 acc[8] = {};

    #pragma unroll
    for (int c = 0; c < 4; ++c) {
        bf16x8 ab0, ab1;
        {
            union { bf16x8 v; unsigned short u[8]; } cv;
            cv.u[0] = f2b(araw[0].x * ns); cv.u[1] = f2b(araw[0].y * ns);
            cv.u[2] = f2b(araw[0].z * ns); cv.u[3] = f2b(araw[0].w * ns);
            cv.u[4] = f2b(araw[1].x * ns); cv.u[5] = f2b(araw[1].y * ns);
            cv.u[6] = f2b(araw[1].z * ns); cv.u[7] = f2b(araw[1].w * ns);
            ab0 = cv.v;
            cv.u[0] = f2b(araw[2].x * ns); cv.u[1] = f2b(araw[2].y * ns);
            cv.u[2] = f2b(araw[2].z * ns); cv.u[3] = f2b(araw[2].w * ns);
            cv.u[4] = f2b(araw[3].x * ns); cv.u[5] = f2b(araw[3].y * ns);
            cv.u[6] = f2b(araw[3].z * ns); cv.u[7] = f2b(araw[3].w * ns);
            ab1 = cv.v;
        }
        if (c < 3) {
            araw[0] = *(const float4*)(xp + (c + 1) * 64 + 0);
            araw[1] = *(const float4*)(xp + (c + 1) * 64 + 4);
            araw[2] = *(const float4*)(xp + (c + 1) * 64 + 32);
            araw[3] = *(const float4*)(xp + (c + 1) * 64 + 36);
        }
        #pragma unroll
        for (int nt = 0; nt < 8; ++nt) {
            bf16x8 b = *(const bf16x8*)(Bs + bbase0 + nt * 16 * 256 + c * 64);
            acc[nt] = __builtin_amdgcn_mfma_f32_16x16x32_bf16(ab0, b, acc[nt], 0, 0, 0);
        }
        #pragma unroll
        for (int nt = 0; nt < 8; ++nt) {
            bf16x8 b = *(const bf16x8*)(Bs + bbase1 + nt * 16 * 256 + c * 64);
            acc[nt] = __builtin_amdgcn_mfma_f32_16x16x32_bf16(ab1, b, acc[nt], 0, 0, 0);
        }
    }

    #pragma unroll
    for (int nt = 0; nt < 8; ++nt) {
        #pragma unroll
        for (int r = 0; r < 4; ++r) {
            int node = node0 + w * 16 + quad * 4 + r;
            if (node < N)
                h1b[(size_t)node * F_HID + nt * 16 + l15] = __float2bfloat16(acc[nt][r]);
        }
    }
}

// ---- SpMM1 + layer-1 epilogue + fused MFMA projection to h2 ----------------
// 16 nodes/block (512 thr), 32 lanes/node: gather h1b rows, activate, store
// fp16 row to LDS As[16][136] (pad->bank-spread, 16B-aligned frags). Then
// wave 0 computes h2[16 nodes][40] = As @ W2t via 12x mfma_f32_16x16x32_f16
// (A-frag: As[l15][kc*32+quad*8..+8); B-frag: W2t[ct*16+l15][same k] from L2).
__global__ __launch_bounds__(512) void spmm1_fused_kernel(
    const __hip_bfloat16* __restrict__ h1b, const int* __restrict__ row_off,
    const int* __restrict__ csr_src, const float* __restrict__ norm_src,
    const float* __restrict__ norm_dst, const float* __restrict__ b1,
    const unsigned short* __restrict__ W2t, unsigned short* __restrict__ h2, int N)
{
    __shared__ unsigned short As[16][136];
    const int t = threadIdx.x;
    const int g = t >> 5;
    const int node = blockIdx.x * 16 + g;
    const int c = (t & 31) << 2;

    if (node < N) {
        const int start = row_off[node];
        const int end = row_off[node + 1];
        float4 acc = make_float4(0.f, 0.f, 0.f, 0.f);
        int j = start;
        for (; j + 8 <= end; j += 8) {
            int s[8];
            #pragma unroll
            for (int i = 0; i < 8; ++i) s[i] = csr_src[j + i];
            ushort4 u[8];
            #pragma unroll
            for (int i = 0; i < 8; ++i)
                u[i] = *(const ushort4*)(h1b + (size_t)s[i] * F_HID + c);
            #pragma unroll
            for (int i = 0; i < 8; ++i) {
                acc.x += b2f(u[i].x);
                acc.y += b2f(u[i].y);
                acc.z += b2f(u[i].z);
                acc.w += b2f(u[i].w);
            }
        }
        for (; j + 2 <= end; j += 2) {
            int s0 = csr_src[j + 0];
            int s1 = csr_src[j + 1];
            ushort4 u0 = *(const ushort4*)(h1b + (size_t)s0 * F_HID + c);
            ushort4 u1 = *(const ushort4*)(h1b + (size_t)s1 * F_HID + c);
            acc.x += b2f(u0.x) + b2f(u1.x);
            acc.y += b2f(u0.y) + b2f(u1.y);
            acc.z += b2f(u0.z) + b2f(u1.z);
            acc.w += b2f(u0.w) + b2f(u1.w);
        }
        if (j < end) {
            int s = csr_src[j];
            ushort4 u = *(const ushort4*)(h1b + (size_t)s * F_HID + c);
            acc.x += b2f(u.x);
            acc.y += b2f(u.y);
            acc.z += b2f(u.z);
            acc.w += b2f(u.w);
        }
        const float nd = norm_dst[node];
        const float ns = norm_src[node];
        float4 bb = *(const float4*)(b1 + c);
        ushort4 o;
        o.x = f2h(fmaxf(fmaf(acc.x, nd, bb.x), 0.f) * ns);
        o.y = f2h(fmaxf(fmaf(acc.y, nd, bb.y), 0.f) * ns);
        o.z = f2h(fmaxf(fmaf(acc.z, nd, bb.z), 0.f) * ns);
        o.w = f2h(fmaxf(fmaf(acc.w, nd, bb.w), 0.f) * ns);
        *(ushort4*)&As[g][c] = o;
    } else {
        ushort4 z = make_ushort4(0, 0, 0, 0);
        *(ushort4*)&As[g][c] = z;
    }
    __syncthreads();
    if (t >= 64) return;

    const int l15 = t & 15;
    const int quad = t >> 4;
    floatx4 co[3] = {};
    #pragma unroll
    for (int kc = 0; kc < 4; ++kc) {
        f16x8 a = *(const f16x8*)&As[l15][kc * 32 + quad * 8];
        #pragma unroll
        for (int ct = 0; ct < 3; ++ct) {
            f16x8 b = *(const f16x8*)(W2t + (size_t)(ct * 16 + l15) * F_HID
                                          + kc * 32 + quad * 8);
            co[ct] = __builtin_amdgcn_mfma_f32_16x16x32_f16(a, b, co[ct], 0, 0, 0);
        }
    }
    const int node0 = blockIdx.x * 16;
    #pragma unroll
    for (int ct = 0; ct < 3; ++ct) {
        int col = ct * 16 + l15;
        if (col < F_CLS) {
            #pragma unroll
            for (int i = 0; i < 4; ++i) {
                int n2 = node0 + quad * 4 + i;
                if (n2 < N) h2[(size_t)n2 * F_CLS + col] = f2h(co[ct][i]);
            }
        }
    }
}

// ---- SpMM2 (CSR, fp16 gather) + epilogue: out = (sum h2[src,:])*nd + b2 ----
// 25 nodes/block, 10 lanes/node (250/256 active), 8-deep gather batching.
__global__ __launch_bounds__(256) void spmm2_csr_kernel(
    const unsigned short* __restrict__ h2, const int* __restrict__ row_off,
    const int* __restrict__ csr_src, const float* __restrict__ norm_dst,
    const float* __restrict__ b2, float* __restrict__ out, int N)
{
    const int t = threadIdx.x;
    if (t >= 250) return;
    const int node = blockIdx.x * 25 + t / 10;
    const int lane = t % 10;
    if (node >= N) return;
    const int c = lane << 2;
    const int start = row_off[node];
    const int end = row_off[node + 1];
    float4 acc = make_float4(0.f, 0.f, 0.f, 0.f);
    int j = start;
    for (; j + 8 <= end; j += 8) {
        int s[8];
        #pragma unroll
        for (int i = 0; i < 8; ++i) s[i] = csr_src[j + i];
        ushort4 u[8];
        #pragma unroll
        for (int i = 0; i < 8; ++i)
            u[i] = *(const ushort4*)(h2 + (size_t)s[i] * F_CLS + c);
        #pragma unroll
        for (int i = 0; i < 8; ++i) {
            acc.x += h2f(u[i].x);
            acc.y += h2f(u[i].y);
            acc.z += h2f(u[i].z);
            acc.w += h2f(u[i].w);
        }
    }
    for (; j + 2 <= end; j += 2) {
        int s0 = csr_src[j + 0];
        int s1 = csr_src[j + 1];
        ushort4 u0 = *(const ushort4*)(h2 + (size_t)s0 * F_CLS + c);
        ushort4 u1 = *(const ushort4*)(h2 + (size_t)s1 * F_CLS + c);
        acc.x += h2f(u0.x) + h2f(u1.x);
        acc.y += h2f(u0.y) + h2f(u1.y);
        acc.z += h2f(u0.z) + h2f(u1.z);
        acc.w += h2f(u0.w) + h2f(u1.w);
    }
    if (j < end) {
        int s = csr_src[j];
        ushort4 u = *(const ushort4*)(h2 + (size_t)s * F_CLS + c);
        acc.x += h2f(u.x);
        acc.y += h2f(u.y);
        acc.z += h2f(u.z);
        acc.w += h2f(u.w);
    }
    float nd = norm_dst[node];
    float4 bb = *(const float4*)(b2 + c);
    float4 r;
    r.x = fmaf(acc.x, nd, bb.x);
    r.y = fmaf(acc.y, nd, bb.y);
    r.z = fmaf(acc.z, nd, bb.z);
    r.w = fmaf(acc.w, nd, bb.w);
    *(float4*)(out + (size_t)node * F_CLS + c) = r;
}

extern "C" void kernel_launch(void* const* d_in, const int* in_sizes, int n_in,
                              void* d_out, int out_size, void* d_ws, size_t ws_size,
                              hipStream_t stream) {
    const float* X   = (const float*)d_in[0];
    const int*   src = (const int*)d_in[1];
    const int*   dst = (const int*)d_in[2];
    const float* W1  = (const float*)d_in[3];
    const float* b1  = (const float*)d_in[4];
    const float* W2  = (const float*)d_in[5];
    const float* b2  = (const float*)d_in[6];
    float* out = (float*)d_out;

    const int N = in_sizes[0] / F_IN;
    const int E = in_sizes[1];
    const int NB = (N + 1023) / 1024;     // scan blocks (<= 256)
    const int NR = (N + RSZ - 1) / RSZ;   // histogram ranges
    const int NRtot = NR * RSZ;

    // workspace layout — keep every array 16B-aligned
    char* w = (char*)d_ws;
    int*   row_off  = (int*)w;                      w += (size_t)(N + 4) * 4;
    int*   blk_sums = (int*)w;                      w += 256 * 4;
    int*   csr_src  = (int*)w;                      w += (size_t)E * 4;
    float* norm_src = (float*)w;                    w += (size_t)N * 4;
    float* norm_dst = (float*)w;                    w += (size_t)N * 4;
    unsigned short* h2 = (unsigned short*)w;        w += (size_t)N * F_CLS * 2;
    __hip_bfloat16* W1t = (__hip_bfloat16*)w;       w += (size_t)F_HID * F_IN * 2;
    unsigned short* W2t = (unsigned short*)w;       w += (size_t)48 * F_HID * 2;
    __hip_bfloat16* h1b = (__hip_bfloat16*)w;       w += (size_t)N * F_HID * 2;
    unsigned* partial_s = (unsigned*)w;             w += (size_t)NR * NSL * RSZ * 4;
    unsigned* partial_d = (unsigned*)w;             w += (size_t)NR * NSL * RSZ * 4;

    hist_kernel<<<dim3(NR * NSL, 2), 256, 0, stream>>>(src, dst, partial_s, partial_d, E);

    scan1_kernel<<<NB, 256, 0, stream>>>(partial_s, partial_d, row_off, blk_sums,
                                         norm_src, norm_dst, N);
    scan2_pack_kernel<<<153, 256, 0, stream>>>(blk_sums, NB, W1, W1t, W2, W2t);
    scan3_slicepref_kernel<<<(NRtot + 255) / 256, 256, 0, stream>>>(
        row_off, blk_sums, partial_d, N, E, NRtot);

    scatter2_kernel<<<NR * NSL, 256, 0, stream>>>(src, dst, partial_d, csr_src, E);

    gemm1_mfma_kernel<<<(N + 127) / 128, 512, 0, stream>>>(X, W1t, norm_src, h1b, N);

    spmm1_fused_kernel<<<(N + 15) / 16, 512, 0, stream>>>(h1b, row_off, csr_src,
                                                          norm_src, norm_dst, b1,
                                                          W2t, h2, N);

    spmm2_csr_kernel<<<(N + 24) / 25, 256, 0, stream>>>(h2, row_off, csr_src,
                                                        norm_dst, b2, out, N);
}

// Round 10
// 299.656 us; speedup vs baseline: 1.2101x; 1.0077x over previous
//
#include <hip/hip_runtime.h>
#include <hip/hip_bf16.h>
#include <math.h>

// GCN 2-layer: h = Ddst^-1/2 A (Dsrc^-1/2 x) W + b, relu between.
// R19: gemm1 latency attack, structure-preserving. R18 confirmed the R16
// config at 302us; budget model puts gemm1 largest (~50us vs 20us floor),
// X-latency-bound: 1-chunk lookahead covers ~300cy of a ~900cy HBM latency.
// Changes (gemm1 only, rest byte-identical to R18 for attribution):
//  (1) 2-deep X prefetch: ar[2][4] double-buffer; chunks 0+1 issued BEFORE
//      the 64KB staging loop (resolve under stage+barrier); chunk c+2
//      issued before chunk c's MFMAs. +16 VGPR (~90-100 < 128 cap @ 4w/EU).
//  (2) norm_src applied in fp32 epilogue (R17 validated numerically) --
//      removes 32 VALU muls per chunk per wave from the serial path.
// LEDGER (R11/R17): hipcc sinks hoisted global loads to minimize VGPR; LDS
// staging is the reliable B path. (R14): device-scope atomicAdd is HBM
// write-through (~32B/op) -- histogram CSR build wins.
// 2x400MB harness poison fills (~119us) sit inside the timed window.

#define F_IN  256
#define F_HID 128
#define F_CLS 40

#define RSZ 8192    // nodes per histogram range (32KB LDS)
#define NSL 32      // edge slices

typedef __bf16 bf16_t;
typedef bf16_t bf16x8 __attribute__((ext_vector_type(8)));
typedef float floatx4 __attribute__((ext_vector_type(4)));
typedef _Float16 f16x8 __attribute__((ext_vector_type(8)));

static __device__ __forceinline__ unsigned short f2b(float f) {
    __hip_bfloat16 h = __float2bfloat16(f);   // RNE
    return __builtin_bit_cast(unsigned short, h);
}
static __device__ __forceinline__ float b2f(unsigned short u) {
    return __uint_as_float((unsigned)u << 16);
}
static __device__ __forceinline__ unsigned short f2h(float f) {
    return __builtin_bit_cast(unsigned short, (_Float16)f);
}
static __device__ __forceinline__ float h2f(unsigned short u) {
    return (float)__builtin_bit_cast(_Float16, u);
}

// ---- histogram partials: block (r, sl, y) counts keys-in-range from slice --
__global__ __launch_bounds__(256) void hist_kernel(
    const int* __restrict__ src, const int* __restrict__ dst,
    unsigned* __restrict__ partial_s, unsigned* __restrict__ partial_d, int E)
{
    __shared__ unsigned h[RSZ];
    const int t = threadIdx.x;
    const int r  = blockIdx.x / NSL;
    const int sl = blockIdx.x % NSL;
    const int lo = r * RSZ;
    const int* __restrict__ keys = blockIdx.y ? dst : src;
    unsigned* __restrict__ part = blockIdx.y ? partial_d : partial_s;

    for (int i = t; i < RSZ; i += 256) h[i] = 0;
    __syncthreads();

    const int slice = (E + NSL - 1) / NSL;
    const int e0 = sl * slice;
    const int e1 = min(E, e0 + slice);

    int e = e0 + t;
    for (; e + 7 * 256 < e1; e += 8 * 256) {
        int k[8];
        #pragma unroll
        for (int i = 0; i < 8; ++i) k[i] = keys[e + i * 256];
        #pragma unroll
        for (int i = 0; i < 8; ++i) {
            unsigned kk = (unsigned)(k[i] - lo);
            if (kk < RSZ) atomicAdd(&h[kk], 1u);
        }
    }
    for (; e < e1; e += 256) {
        unsigned kk = (unsigned)(keys[e] - lo);
        if (kk < RSZ) atomicAdd(&h[kk], 1u);
    }
    __syncthreads();

    unsigned* dst_p = part + (size_t)blockIdx.x * RSZ;
    for (int i = t; i < RSZ; i += 256) dst_p[i] = h[i];
}

// ---- scan1: reduce partials -> norms + block-local exclusive scan ----------
__global__ __launch_bounds__(256) void scan1_kernel(
    const unsigned* __restrict__ partial_s, const unsigned* __restrict__ partial_d,
    int* __restrict__ row_off, int* __restrict__ blk_sums,
    float* __restrict__ norm_src, float* __restrict__ norm_dst, int N)
{
    __shared__ int s[256];
    const int t = threadIdx.x;
    const int base = blockIdx.x * 1024 + t * 4;

    unsigned ss0 = 0, ss1 = 0, ss2 = 0, ss3 = 0;
    unsigned sd0 = 0, sd1 = 0, sd2 = 0, sd3 = 0;
    {
        // base..base+3 never cross an RSZ boundary (both multiples of 4)
        const int r = base / RSZ;
        const int off = base & (RSZ - 1);
        const unsigned* ps = partial_s + (size_t)r * NSL * RSZ + off;
        const unsigned* pd = partial_d + (size_t)r * NSL * RSZ + off;
        #pragma unroll
        for (int sl = 0; sl < NSL; ++sl) {
            uint4 a = *(const uint4*)(ps + (size_t)sl * RSZ);
            uint4 b = *(const uint4*)(pd + (size_t)sl * RSZ);
            ss0 += a.x; ss1 += a.y; ss2 += a.z; ss3 += a.w;
            sd0 += b.x; sd1 += b.y; sd2 += b.z; sd3 += b.w;
        }
    }
    if (base + 0 < N) {
        norm_src[base + 0] = ss0 ? 1.0f / sqrtf((float)ss0) : 0.0f;
        norm_dst[base + 0] = sd0 ? 1.0f / sqrtf((float)sd0) : 0.0f;
    }
    if (base + 1 < N) {
        norm_src[base + 1] = ss1 ? 1.0f / sqrtf((float)ss1) : 0.0f;
        norm_dst[base + 1] = sd1 ? 1.0f / sqrtf((float)sd1) : 0.0f;
    }
    if (base + 2 < N) {
        norm_src[base + 2] = ss2 ? 1.0f / sqrtf((float)ss2) : 0.0f;
        norm_dst[base + 2] = sd2 ? 1.0f / sqrtf((float)sd2) : 0.0f;
    }
    if (base + 3 < N) {
        norm_src[base + 3] = ss3 ? 1.0f / sqrtf((float)ss3) : 0.0f;
        norm_dst[base + 3] = sd3 ? 1.0f / sqrtf((float)sd3) : 0.0f;
    }

    int v0 = (base + 0 < N) ? (int)sd0 : 0;
    int v1 = (base + 1 < N) ? (int)sd1 : 0;
    int v2 = (base + 2 < N) ? (int)sd2 : 0;
    int v3 = (base + 3 < N) ? (int)sd3 : 0;
    int local = v0 + v1 + v2 + v3;
    s[t] = local;
    __syncthreads();
    for (int off = 1; off < 256; off <<= 1) {
        int x = (t >= off) ? s[t - off] : 0;
        __syncthreads();
        s[t] += x;
        __syncthreads();
    }
    int excl = s[t] - local;
    if (t == 255) blk_sums[blockIdx.x] = s[t];
    if (base + 0 < N) row_off[base + 0] = excl;
    if (base + 1 < N) row_off[base + 1] = excl + v0;
    if (base + 2 < N) row_off[base + 2] = excl + v0 + v1;
    if (base + 3 < N) row_off[base + 3] = excl + v0 + v1 + v2;
}

// ---- scan2 (block 0) + pack W1->W1t (blocks 1..128) + W2->W2t (129..152) ---
// W1t [128][256] bf16 n-major k-contig; W2t [48][128] fp16 n-major k-contig
// (rows 40..47 zero) -- both match the gemm1/MFMA B-frag layout.
__global__ __launch_bounds__(256) void scan2_pack_kernel(
    int* __restrict__ blk_sums, int B,
    const float* __restrict__ W1, __hip_bfloat16* __restrict__ W1t,
    const float* __restrict__ W2, unsigned short* __restrict__ W2t)
{
    const int t = threadIdx.x;
    if (blockIdx.x > 128) {
        int idx = (blockIdx.x - 129) * 256 + t;   // 0..6143
        int n = idx >> 7;                         // 0..47
        int k = idx & 127;
        W2t[idx] = (n < F_CLS) ? f2h(W2[(size_t)k * F_CLS + n]) : (unsigned short)0;
        return;
    }
    if (blockIdx.x > 0) {
        int idx = (blockIdx.x - 1) * 256 + t;     // 0..32767
        int n = idx >> 8;
        int k = idx & 255;
        W1t[idx] = __float2bfloat16(W1[(size_t)k * F_HID + n]);
        return;
    }
    __shared__ int s[256];
    int local = (t < B) ? blk_sums[t] : 0;
    s[t] = local;
    __syncthreads();
    for (int off = 1; off < 256; off <<= 1) {
        int x = (t >= off) ? s[t - off] : 0;
        __syncthreads();
        s[t] += x;
        __syncthreads();
    }
    if (t < B) blk_sums[t] = s[t] - local;   // exclusive
}

// ---- scan3+slicepref fused: finalize row_off and convert partial_d counts
//      into absolute CSR cursors (in-place exclusive scan over slices) -------
__global__ __launch_bounds__(256) void scan3_slicepref_kernel(
    int* __restrict__ row_off, const int* __restrict__ blk_sums,
    unsigned* __restrict__ partial_d, int N, int E, int NRtot)
{
    const int idx = blockIdx.x * 256 + threadIdx.x;   // node id (incl. pad)
    if (idx >= NRtot) return;
    unsigned run = 0;
    if (idx < N) {
        int v = row_off[idx] + blk_sums[idx >> 10];
        row_off[idx] = v;
        run = (unsigned)v;
    }
    if (idx == N) row_off[N] = E;
    const int r = idx / RSZ;
    const int i = idx & (RSZ - 1);
    unsigned* p = partial_d + (size_t)r * NSL * RSZ + i;
    #pragma unroll
    for (int sl = 0; sl < NSL; ++sl) {
        unsigned c = p[(size_t)sl * RSZ];
        p[(size_t)sl * RSZ] = run;
        run += c;
    }
}

// ---- scatter edges into CSR via LDS cursors (no global atomics) ------------
__global__ __launch_bounds__(256) void scatter2_kernel(
    const int* __restrict__ src, const int* __restrict__ dst,
    const unsigned* __restrict__ pref, int* __restrict__ csr_src, int E)
{
    __shared__ unsigned cur[RSZ];
    const int t = threadIdx.x;
    const int r  = blockIdx.x / NSL;
    const int sl = blockIdx.x % NSL;
    const int lo = r * RSZ;
    const unsigned* p = pref + (size_t)blockIdx.x * RSZ;   // [r][sl][.]

    for (int i = t; i < RSZ; i += 256) cur[i] = p[i];
    __syncthreads();

    const int slice = (E + NSL - 1) / NSL;
    const int e0 = sl * slice;
    const int e1 = min(E, e0 + slice);

    int e = e0 + t;
    for (; e + 7 * 256 < e1; e += 8 * 256) {
        int d[8], s[8];
        #pragma unroll
        for (int i = 0; i < 8; ++i) { d[i] = dst[e + i * 256]; s[i] = src[e + i * 256]; }
        #pragma unroll
        for (int i = 0; i < 8; ++i) {
            unsigned k = (unsigned)(d[i] - lo);
            if (k < RSZ) {
                unsigned pos = atomicAdd(&cur[k], 1u);
                csr_src[pos] = s[i];
            }
        }
    }
    for (; e < e1; e += 256) {
        unsigned k = (unsigned)(dst[e] - lo);
        if (k < RSZ) {
            unsigned pos = atomicAdd(&cur[k], 1u);
            csr_src[pos] = src[e];
        }
    }
}

// ---- GEMM1 (MFMA): h1b[N,128] = bf16( (X @ W1)*ns ) ------------------------
// R12 structure + R19 latency fixes: BM=128, 512 threads (8 waves), full
// W1t (64KB) staged to LDS once (XOR-swizzled, conflict-free ds_read_b128),
// one barrier. NEW: 2-deep X prefetch (chunks 0,1 issued before staging;
// c+2 issued before chunk c's MFMAs) and ns applied in the fp32 epilogue.
__global__ __launch_bounds__(512, 4) void gemm1_mfma_kernel(
    const float* __restrict__ X, const __hip_bfloat16* __restrict__ W1t,
    const float* __restrict__ norm_src, __hip_bfloat16* __restrict__ h1b, int N)
{
    __shared__ __hip_bfloat16 Bs[128 * 256];   // 64KB, rows XOR-swizzled
    const int t = threadIdx.x;
    const int node0 = blockIdx.x * 128;
    const int lane = t & 63;
    const int w = t >> 6;               // wave 0..7 -> 16 rows each
    const int l15 = lane & 15;
    const int quad = lane >> 4;

    const int arow = node0 + w * 16 + l15;
    const int arow_c = (arow < N) ? arow : (N - 1);   // clamped rows produce
    const float* xp = X + (size_t)arow_c * F_IN + quad * 8;  // unused outputs

    // 2-deep prefetch: issue chunks 0 AND 1 before staging; they resolve
    // under the 64KB stage + barrier.
    float4 ar[2][4];
    ar[0][0] = *(const float4*)(xp + 0);
    ar[0][1] = *(const float4*)(xp + 4);
    ar[0][2] = *(const float4*)(xp + 32);
    ar[0][3] = *(const float4*)(xp + 36);
    ar[1][0] = *(const float4*)(xp + 64 + 0);
    ar[1][1] = *(const float4*)(xp + 64 + 4);
    ar[1][2] = *(const float4*)(xp + 64 + 32);
    ar[1][3] = *(const float4*)(xp + 64 + 36);

    // stage W1t[128][256] -> LDS, reg-staged so dest can carry the XOR swizzle
    // (element index bits 3..5 ^= row&7). 4096 16B-chunks / 512 threads = 8.
    #pragma unroll
    for (int i = 0; i < 8; ++i) {
        int idx = i * 512 + t;
        int row = idx >> 5;             // 0..127
        int ch  = idx & 31;             // 16B chunk within row
        uint4 v = *(const uint4*)(W1t + (size_t)row * F_IN + ch * 8);
        int d = row * 256 + ((ch * 8) ^ ((row & 7) << 3));
        *(uint4*)(Bs + d) = v;
    }
    __syncthreads();

    // per-lane swizzled B base offsets (elements); row = nt*16 + l15 so
    // row&7 == l15&7 independent of nt; c*64 sits above the swizzled bits.
    const int swz = (l15 & 7) << 3;
    const int bbase0 = l15 * 256 + ((quad * 8) ^ swz);
    const int bbase1 = l15 * 256 + ((32 + quad * 8) ^ swz);

    floatx4 acc[8] = {};

    #pragma unroll
    for (int c = 0; c < 4; ++c) {
        const int p = c & 1;
        bf16x8 ab0, ab1;
        {
            union { bf16x8 v; unsigned short u[8]; } cv;
            cv.u[0] = f2b(ar[p][0].x); cv.u[1] = f2b(ar[p][0].y);
            cv.u[2] = f2b(ar[p][0].z); cv.u[3] = f2b(ar[p][0].w);
            cv.u[4] = f2b(ar[p][1].x); cv.u[5] = f2b(ar[p][1].y);
            cv.u[6] = f2b(ar[p][1].z); cv.u[7] = f2b(ar[p][1].w);
            ab0 = cv.v;
            cv.u[0] = f2b(ar[p][2].x); cv.u[1] = f2b(ar[p][2].y);
            cv.u[2] = f2b(ar[p][2].z); cv.u[3] = f2b(ar[p][2].w);
            cv.u[4] = f2b(ar[p][3].x); cv.u[5] = f2b(ar[p][3].y);
            cv.u[6] = f2b(ar[p][3].z); cv.u[7] = f2b(ar[p][3].w);
            ab1 = cv.v;
        }
        if (c < 2) {
            // prefetch chunk c+2 into the buffer just consumed
            ar[p][0] = *(const float4*)(xp + (c + 2) * 64 + 0);
            ar[p][1] = *(const float4*)(xp + (c + 2) * 64 + 4);
            ar[p][2] = *(const float4*)(xp + (c + 2) * 64 + 32);
            ar[p][3] = *(const float4*)(xp + (c + 2) * 64 + 36);
        }
        #pragma unroll
        for (int nt = 0; nt < 8; ++nt) {
            bf16x8 b = *(const bf16x8*)(Bs + bbase0 + nt * 16 * 256 + c * 64);
            acc[nt] = __builtin_amdgcn_mfma_f32_16x16x32_bf16(ab0, b, acc[nt], 0, 0, 0);
        }
        #pragma unroll
        for (int nt = 0; nt < 8; ++nt) {
            bf16x8 b = *(const bf16x8*)(Bs + bbase1 + nt * 16 * 256 + c * 64);
            acc[nt] = __builtin_amdgcn_mfma_f32_16x16x32_bf16(ab1, b, acc[nt], 0, 0, 0);
        }
    }

    // epilogue: ns of the OUTPUT row (C row = w*16 + quad*4 + r), fp32
    #pragma unroll
    for (int r = 0; r < 4; ++r) {
        int node = node0 + w * 16 + quad * 4 + r;
        if (node < N) {
            float ns = norm_src[node];
            #pragma unroll
            for (int nt = 0; nt < 8; ++nt)
                h1b[(size_t)node * F_HID + nt * 16 + l15] =
                    __float2bfloat16(acc[nt][r] * ns);
        }
    }
}

// ---- SpMM1 + layer-1 epilogue + fused MFMA projection to h2 ----------------
// 16 nodes/block (512 thr), 32 lanes/node: gather h1b rows, activate, store
// fp16 row to LDS As[16][136] (pad->bank-spread, 16B-aligned frags). Then
// wave 0 computes h2[16 nodes][40] = As @ W2t via 12x mfma_f32_16x16x32_f16
// (A-frag: As[l15][kc*32+quad*8..+8); B-frag: W2t[ct*16+l15][same k] from L2).
__global__ __launch_bounds__(512) void spmm1_fused_kernel(
    const __hip_bfloat16* __restrict__ h1b, const int* __restrict__ row_off,
    const int* __restrict__ csr_src, const float* __restrict__ norm_src,
    const float* __restrict__ norm_dst, const float* __restrict__ b1,
    const unsigned short* __restrict__ W2t, unsigned short* __restrict__ h2, int N)
{
    __shared__ unsigned short As[16][136];
    const int t = threadIdx.x;
    const int g = t >> 5;
    const int node = blockIdx.x * 16 + g;
    const int c = (t & 31) << 2;

    if (node < N) {
        const int start = row_off[node];
        const int end = row_off[node + 1];
        float4 acc = make_float4(0.f, 0.f, 0.f, 0.f);
        int j = start;
        for (; j + 8 <= end; j += 8) {
            int s[8];
            #pragma unroll
            for (int i = 0; i < 8; ++i) s[i] = csr_src[j + i];
            ushort4 u[8];
            #pragma unroll
            for (int i = 0; i < 8; ++i)
                u[i] = *(const ushort4*)(h1b + (size_t)s[i] * F_HID + c);
            #pragma unroll
            for (int i = 0; i < 8; ++i) {
                acc.x += b2f(u[i].x);
                acc.y += b2f(u[i].y);
                acc.z += b2f(u[i].z);
                acc.w += b2f(u[i].w);
            }
        }
        for (; j + 2 <= end; j += 2) {
            int s0 = csr_src[j + 0];
            int s1 = csr_src[j + 1];
            ushort4 u0 = *(const ushort4*)(h1b + (size_t)s0 * F_HID + c);
            ushort4 u1 = *(const ushort4*)(h1b + (size_t)s1 * F_HID + c);
            acc.x += b2f(u0.x) + b2f(u1.x);
            acc.y += b2f(u0.y) + b2f(u1.y);
            acc.z += b2f(u0.z) + b2f(u1.z);
            acc.w += b2f(u0.w) + b2f(u1.w);
        }
        if (j < end) {
            int s = csr_src[j];
            ushort4 u = *(const ushort4*)(h1b + (size_t)s * F_HID + c);
            acc.x += b2f(u.x);
            acc.y += b2f(u.y);
            acc.z += b2f(u.z);
            acc.w += b2f(u.w);
        }
        const float nd = norm_dst[node];
        const float ns = norm_src[node];
        float4 bb = *(const float4*)(b1 + c);
        ushort4 o;
        o.x = f2h(fmaxf(fmaf(acc.x, nd, bb.x), 0.f) * ns);
        o.y = f2h(fmaxf(fmaf(acc.y, nd, bb.y), 0.f) * ns);
        o.z = f2h(fmaxf(fmaf(acc.z, nd, bb.z), 0.f) * ns);
        o.w = f2h(fmaxf(fmaf(acc.w, nd, bb.w), 0.f) * ns);
        *(ushort4*)&As[g][c] = o;
    } else {
        ushort4 z = make_ushort4(0, 0, 0, 0);
        *(ushort4*)&As[g][c] = z;
    }
    __syncthreads();
    if (t >= 64) return;

    const int l15 = t & 15;
    const int quad = t >> 4;
    floatx4 co[3] = {};
    #pragma unroll
    for (int kc = 0; kc < 4; ++kc) {
        f16x8 a = *(const f16x8*)&As[l15][kc * 32 + quad * 8];
        #pragma unroll
        for (int ct = 0; ct < 3; ++ct) {
            f16x8 b = *(const f16x8*)(W2t + (size_t)(ct * 16 + l15) * F_HID
                                          + kc * 32 + quad * 8);
            co[ct] = __builtin_amdgcn_mfma_f32_16x16x32_f16(a, b, co[ct], 0, 0, 0);
        }
    }
    const int node0 = blockIdx.x * 16;
    #pragma unroll
    for (int ct = 0; ct < 3; ++ct) {
        int col = ct * 16 + l15;
        if (col < F_CLS) {
            #pragma unroll
            for (int i = 0; i < 4; ++i) {
                int n2 = node0 + quad * 4 + i;
                if (n2 < N) h2[(size_t)n2 * F_CLS + col] = f2h(co[ct][i]);
            }
        }
    }
}

// ---- SpMM2 (CSR, fp16 gather) + epilogue: out = (sum h2[src,:])*nd + b2 ----
// 25 nodes/block, 10 lanes/node (250/256 active), 8-deep gather batching.
__global__ __launch_bounds__(256) void spmm2_csr_kernel(
    const unsigned short* __restrict__ h2, const int* __restrict__ row_off,
    const int* __restrict__ csr_src, const float* __restrict__ norm_dst,
    const float* __restrict__ b2, float* __restrict__ out, int N)
{
    const int t = threadIdx.x;
    if (t >= 250) return;
    const int node = blockIdx.x * 25 + t / 10;
    const int lane = t % 10;
    if (node >= N) return;
    const int c = lane << 2;
    const int start = row_off[node];
    const int end = row_off[node + 1];
    float4 acc = make_float4(0.f, 0.f, 0.f, 0.f);
    int j = start;
    for (; j + 8 <= end; j += 8) {
        int s[8];
        #pragma unroll
        for (int i = 0; i < 8; ++i) s[i] = csr_src[j + i];
        ushort4 u[8];
        #pragma unroll
        for (int i = 0; i < 8; ++i)
            u[i] = *(const ushort4*)(h2 + (size_t)s[i] * F_CLS + c);
        #pragma unroll
        for (int i = 0; i < 8; ++i) {
            acc.x += h2f(u[i].x);
            acc.y += h2f(u[i].y);
            acc.z += h2f(u[i].z);
            acc.w += h2f(u[i].w);
        }
    }
    for (; j + 2 <= end; j += 2) {
        int s0 = csr_src[j + 0];
        int s1 = csr_src[j + 1];
        ushort4 u0 = *(const ushort4*)(h2 + (size_t)s0 * F_CLS + c);
        ushort4 u1 = *(const ushort4*)(h2 + (size_t)s1 * F_CLS + c);
        acc.x += h2f(u0.x) + h2f(u1.x);
        acc.y += h2f(u0.y) + h2f(u1.y);
        acc.z += h2f(u0.z) + h2f(u1.z);
        acc.w += h2f(u0.w) + h2f(u1.w);
    }
    if (j < end) {
        int s = csr_src[j];
        ushort4 u = *(const ushort4*)(h2 + (size_t)s * F_CLS + c);
        acc.x += h2f(u.x);
        acc.y += h2f(u.y);
        acc.z += h2f(u.z);
        acc.w += h2f(u.w);
    }
    float nd = norm_dst[node];
    float4 bb = *(const float4*)(b2 + c);
    float4 r;
    r.x = fmaf(acc.x, nd, bb.x);
    r.y = fmaf(acc.y, nd, bb.y);
    r.z = fmaf(acc.z, nd, bb.z);
    r.w = fmaf(acc.w, nd, bb.w);
    *(float4*)(out + (size_t)node * F_CLS + c) = r;
}

extern "C" void kernel_launch(void* const* d_in, const int* in_sizes, int n_in,
                              void* d_out, int out_size, void* d_ws, size_t ws_size,
                              hipStream_t stream) {
    const float* X   = (const float*)d_in[0];
    const int*   src = (const int*)d_in[1];
    const int*   dst = (const int*)d_in[2];
    const float* W1  = (const float*)d_in[3];
    const float* b1  = (const float*)d_in[4];
    const float* W2  = (const float*)d_in[5];
    const float* b2  = (const float*)d_in[6];
    float* out = (float*)d_out;

    const int N = in_sizes[0] / F_IN;
    const int E = in_sizes[1];
    const int NB = (N + 1023) / 1024;     // scan blocks (<= 256)
    const int NR = (N + RSZ - 1) / RSZ;   // histogram ranges
    const int NRtot = NR * RSZ;

    // workspace layout — keep every array 16B-aligned
    char* w = (char*)d_ws;
    int*   row_off  = (int*)w;                      w += (size_t)(N + 4) * 4;
    int*   blk_sums = (int*)w;                      w += 256 * 4;
    int*   csr_src  = (int*)w;                      w += (size_t)E * 4;
    float* norm_src = (float*)w;                    w += (size_t)N * 4;
    float* norm_dst = (float*)w;                    w += (size_t)N * 4;
    unsigned short* h2 = (unsigned short*)w;        w += (size_t)N * F_CLS * 2;
    __hip_bfloat16* W1t = (__hip_bfloat16*)w;       w += (size_t)F_HID * F_IN * 2;
    unsigned short* W2t = (unsigned short*)w;       w += (size_t)48 * F_HID * 2;
    __hip_bfloat16* h1b = (__hip_bfloat16*)w;       w += (size_t)N * F_HID * 2;
    unsigned* partial_s = (unsigned*)w;             w += (size_t)NR * NSL * RSZ * 4;
    unsigned* partial_d = (unsigned*)w;             w += (size_t)NR * NSL * RSZ * 4;

    hist_kernel<<<dim3(NR * NSL, 2), 256, 0, stream>>>(src, dst, partial_s, partial_d, E);

    scan1_kernel<<<NB, 256, 0, stream>>>(partial_s, partial_d, row_off, blk_sums,
                                         norm_src, norm_dst, N);
    scan2_pack_kernel<<<153, 256, 0, stream>>>(blk_sums, NB, W1, W1t, W2, W2t);
    scan3_slicepref_kernel<<<(NRtot + 255) / 256, 256, 0, stream>>>(
        row_off, blk_sums, partial_d, N, E, NRtot);

    scatter2_kernel<<<NR * NSL, 256, 0, stream>>>(src, dst, partial_d, csr_src, E);

    gemm1_mfma_kernel<<<(N + 127) / 128, 512, 0, stream>>>(X, W1t, norm_src, h1b, N);

    spmm1_fused_kernel<<<(N + 15) / 16, 512, 0, stream>>>(h1b, row_off, csr_src,
                                                          norm_src, norm_dst, b1,
                                                          W2t, h2, N);

    spmm2_csr_kernel<<<(N + 24) / 25, 256, 0, stream>>>(h2, row_off, csr_src,
                                                        norm_dst, b2, out, N);
}